// Round 5
// baseline (156.119 us; speedup 1.0000x reference)
//
#include <hip/hip_runtime.h>
#include <hip/hip_fp16.h>
#include <math.h>

#define IN_CH 32
#define K_OUT 4
#define NBD 8                 // dst buckets == XCDs; z-chunk 3.2MB
#define NBS 8                 // src sub-buckets; x-chunk 0.8MB
#define NBK (NBD * NBS)       // 64 buckets, key = dstb*8 + srcb
#define SORT_TILE 4096
#define SORT_THREADS 256
#define EPT (SORT_TILE / SORT_THREADS)

// meta layout (ints): ghist[0..63], boff[64..128] (65 vals), gcur[136..199]
#define M_GH 0
#define M_BO 64
#define M_GC 136

// ---------------------------------------------------------------------------
// z[n][k][i] = sum_j T[k][i][j] * x[n][j]
// ---------------------------------------------------------------------------
__global__ void precompute_z_kernel(const float* __restrict__ x,
                                    const float* __restrict__ T,
                                    float* __restrict__ z,
                                    int n_nodes) {
    __shared__ float Ts[K_OUT * IN_CH * IN_CH];
    for (int t = threadIdx.x; t < K_OUT * IN_CH * IN_CH; t += blockDim.x)
        Ts[t] = T[t];
    __syncthreads();

    const int ki = threadIdx.x;          // 0..127 -> k = ki>>5, i = ki&31
    const float* Trow = Ts + ki * IN_CH;

    for (int n = blockIdx.x; n < n_nodes; n += gridDim.x) {
        const float* xr = x + (size_t)n * IN_CH;
        float sum = 0.f;
#pragma unroll
        for (int j = 0; j < IN_CH; ++j)
            sum = fmaf(Trow[j], xr[j], sum);
        z[(size_t)n * (K_OUT * IN_CH) + ki] = sum;
    }
}

// ---------------------------------------------------------------------------
// 2D bucket sort (dst-range major, src-range minor). All writes coalesced.
// ---------------------------------------------------------------------------
__global__ void zero_meta_kernel(int* __restrict__ meta) {
    meta[threadIdx.x] = 0;   // 256 ints
}

__global__ void hist_kernel(const int* __restrict__ src,
                            const int* __restrict__ dst,
                            int* __restrict__ meta,
                            int n_edges, int n_nodes) {
    __shared__ int lcnt[NBK];
    if (threadIdx.x < NBK) lcnt[threadIdx.x] = 0;
    __syncthreads();
    for (int e = blockIdx.x * blockDim.x + threadIdx.x; e < n_edges;
         e += gridDim.x * blockDim.x) {
        int b = (dst[e] * NBD) / n_nodes * NBS + (src[e] * NBS) / n_nodes;
        atomicAdd(&lcnt[b], 1);
    }
    __syncthreads();
    if (threadIdx.x < NBK) atomicAdd(&meta[M_GH + threadIdx.x], lcnt[threadIdx.x]);
}

__global__ void scan_kernel(int* __restrict__ meta) {
    if (threadIdx.x == 0) {
        int run = 0;
        for (int b = 0; b < NBK; ++b) {
            meta[M_BO + b] = run;
            meta[M_GC + b] = run;
            run += meta[M_GH + b];
        }
        meta[M_BO + NBK] = run;
    }
}

// LDS-staged scatter; rec entries packed src<<16|dst (requires n_nodes<65536).
__global__ __launch_bounds__(SORT_THREADS)
void scatter_kernel(const int* __restrict__ src,
                    const int* __restrict__ dst,
                    int* __restrict__ meta,
                    unsigned int* __restrict__ rec,
                    int* __restrict__ p,
                    int n_edges, int n_nodes) {
    __shared__ unsigned int lrec[SORT_TILE];   // 16 KB
    __shared__ int lcnt[NBK];
    __shared__ int lofs[NBK + 1];
    __shared__ int lbase[NBK];

    const int tid = threadIdx.x;
    const int tile0 = blockIdx.x * SORT_TILE;
    const int tile_cnt = min(SORT_TILE, n_edges - tile0);

    if (tid < NBK) lcnt[tid] = 0;
    __syncthreads();

    int my_rank[EPT], my_b[EPT];
    unsigned int my_rec[EPT];
#pragma unroll
    for (int i = 0; i < EPT; ++i) {
        int e = tile0 + i * SORT_THREADS + tid;     // coalesced
        if (e < n_edges) {
            int s = src[e];
            int d = dst[e];
            int b = (d * NBD) / n_nodes * NBS + (s * NBS) / n_nodes;
            my_b[i] = b;
            my_rec[i] = ((unsigned int)s << 16) | (unsigned int)d;
            my_rank[i] = atomicAdd(&lcnt[b], 1);
        } else {
            my_b[i] = -1;
        }
    }
    __syncthreads();
    if (tid == 0) {
        int run = 0;
        for (int b = 0; b < NBK; ++b) { lofs[b] = run; run += lcnt[b]; }
        lofs[NBK] = run;
    }
    if (tid < NBK) lbase[tid] = atomicAdd(&meta[M_GC + tid], lcnt[tid]);
    __syncthreads();

#pragma unroll
    for (int i = 0; i < EPT; ++i) {
        if (my_b[i] >= 0) {
            int b = my_b[i];
            lrec[lofs[b] + my_rank[i]] = my_rec[i];
            int e = tile0 + i * SORT_THREADS + tid;
            p[e] = lbase[b] + my_rank[i];           // coalesced (indexed by e)
        }
    }
    __syncthreads();

    // flat segment copy: binary-search bucket of LDS slot i, write contiguous
    for (int i = tid; i < tile_cnt; i += SORT_THREADS) {
        int loB = 0, hiB = NBK - 1;
        while (loB < hiB) {
            int mid = (loB + hiB + 1) >> 1;
            if (lofs[mid] <= i) loB = mid; else hiB = mid - 1;
        }
        rec[lbase[loB] + (i - lofs[loB])] = lrec[i];
    }
}

// ---------------------------------------------------------------------------
// Main edge kernel: 2D-sorted order, XCD-affine (blockIdx&7 = dst bucket).
// Working set per instant: z-chunk 3.2MB + x-chunk 0.8MB ~= one XCD L2.
// Quad per edge; res written fp16 coalesced.
// ---------------------------------------------------------------------------
__global__ __launch_bounds__(256)
void edge_kernel_sorted(const float* __restrict__ x,
                        const float* __restrict__ z,
                        const unsigned int* __restrict__ rec,
                        const int* __restrict__ boff,
                        __half* __restrict__ res) {
    const int xcd = blockIdx.x & 7;
    const int wid = blockIdx.x >> 3;
    const int nw  = gridDim.x >> 3;
    const int lo = boff[xcd * NBS];
    const int hi = boff[(xcd + 1) * NBS];
    const int tq = threadIdx.x >> 2;   // 0..63
    const int l  = threadIdx.x & 3;

    for (int base = lo + wid * 64; base < hi; base += nw * 64) {
        const int pos = base + tq;
        if (pos >= hi) break;

        const unsigned int r = rec[pos];   // 4 lanes same 4B: broadcast
        const int s = r >> 16;
        const int d = r & 0xffffu;

        const float4* xs = (const float4*)(x + (size_t)s * IN_CH) + l * 2;
        const float4* zd = (const float4*)(z + (size_t)d * (K_OUT * IN_CH)) + l * 2;

        float4 xa = xs[0];
        float4 xb = xs[1];
        float4 z0a = zd[0],  z0b = zd[1];
        float4 z1a = zd[8],  z1b = zd[9];
        float4 z2a = zd[16], z2b = zd[17];
        float4 z3a = zd[24], z3b = zd[25];

        float p0 = 0.f, p1 = 0.f, p2 = 0.f, p3 = 0.f;
        p0 = fmaf(xa.x, z0a.x, p0); p0 = fmaf(xa.y, z0a.y, p0);
        p0 = fmaf(xa.z, z0a.z, p0); p0 = fmaf(xa.w, z0a.w, p0);
        p0 = fmaf(xb.x, z0b.x, p0); p0 = fmaf(xb.y, z0b.y, p0);
        p0 = fmaf(xb.z, z0b.z, p0); p0 = fmaf(xb.w, z0b.w, p0);

        p1 = fmaf(xa.x, z1a.x, p1); p1 = fmaf(xa.y, z1a.y, p1);
        p1 = fmaf(xa.z, z1a.z, p1); p1 = fmaf(xa.w, z1a.w, p1);
        p1 = fmaf(xb.x, z1b.x, p1); p1 = fmaf(xb.y, z1b.y, p1);
        p1 = fmaf(xb.z, z1b.z, p1); p1 = fmaf(xb.w, z1b.w, p1);

        p2 = fmaf(xa.x, z2a.x, p2); p2 = fmaf(xa.y, z2a.y, p2);
        p2 = fmaf(xa.z, z2a.z, p2); p2 = fmaf(xa.w, z2a.w, p2);
        p2 = fmaf(xb.x, z2b.x, p2); p2 = fmaf(xb.y, z2b.y, p2);
        p2 = fmaf(xb.z, z2b.z, p2); p2 = fmaf(xb.w, z2b.w, p2);

        p3 = fmaf(xa.x, z3a.x, p3); p3 = fmaf(xa.y, z3a.y, p3);
        p3 = fmaf(xa.z, z3a.z, p3); p3 = fmaf(xa.w, z3a.w, p3);
        p3 = fmaf(xb.x, z3b.x, p3); p3 = fmaf(xb.y, z3b.y, p3);
        p3 = fmaf(xb.z, z3b.z, p3); p3 = fmaf(xb.w, z3b.w, p3);

        float send01 = (l & 1) ? p0 : p1;
        float recv01 = __shfl_xor(send01, 1);
        float a01 = ((l & 1) ? p1 : p0) + recv01;
        float send23 = (l & 1) ? p2 : p3;
        float recv23 = __shfl_xor(send23, 1);
        float a23 = ((l & 1) ? p3 : p2) + recv23;
        float send = (l & 2) ? a01 : a23;
        float recv = __shfl_xor(send, 2);
        float v = ((l & 2) ? a23 : a01) + recv;   // lane l = maps[e][l]

        res[(size_t)pos * 4 + l] = __float2half(tanhf(v));  // coalesced fp16
    }
}

// out[e] = cvt_fp32(res_h4[p[e]]) : random access is an 8B READ; writes coalesced.
__global__ void permute_kernel(const __half* __restrict__ res,
                               const int* __restrict__ p,
                               float4* __restrict__ out4,
                               int n_edges) {
    int e = blockIdx.x * blockDim.x + threadIdx.x;
    if (e >= n_edges) return;
    uint2 v = ((const uint2*)res)[p[e]];
    __half2 h01 = *(__half2*)&v.x;
    __half2 h23 = *(__half2*)&v.y;
    float2 f01 = __half22float2(h01);
    float2 f23 = __half22float2(h23);
    out4[e] = make_float4(f01.x, f01.y, f23.x, f23.y);
}

// ---------------------------------------------------------------------------
// Tier-2 (ws fits z only): unsorted quad kernel.
// ---------------------------------------------------------------------------
__global__ __launch_bounds__(256)
void edge_kernel_quad(const float* __restrict__ x,
                      const float* __restrict__ z,
                      const int* __restrict__ src,
                      const int* __restrict__ dst,
                      float* __restrict__ out,
                      int n_edges) {
    const int t = blockIdx.x * blockDim.x + threadIdx.x;
    const int e = t >> 2;
    const int l = t & 3;
    if (e >= n_edges) return;

    const int s = src[e];
    const int d = dst[e];

    const float4* xs = (const float4*)(x + (size_t)s * IN_CH) + l * 2;
    const float4* zd = (const float4*)(z + (size_t)d * (K_OUT * IN_CH)) + l * 2;

    float4 xa = xs[0];
    float4 xb = xs[1];
    float4 z0a = zd[0],  z0b = zd[1];
    float4 z1a = zd[8],  z1b = zd[9];
    float4 z2a = zd[16], z2b = zd[17];
    float4 z3a = zd[24], z3b = zd[25];

    float p0 = 0.f, p1 = 0.f, p2 = 0.f, p3 = 0.f;
    p0 = fmaf(xa.x, z0a.x, p0); p0 = fmaf(xa.y, z0a.y, p0);
    p0 = fmaf(xa.z, z0a.z, p0); p0 = fmaf(xa.w, z0a.w, p0);
    p0 = fmaf(xb.x, z0b.x, p0); p0 = fmaf(xb.y, z0b.y, p0);
    p0 = fmaf(xb.z, z0b.z, p0); p0 = fmaf(xb.w, z0b.w, p0);

    p1 = fmaf(xa.x, z1a.x, p1); p1 = fmaf(xa.y, z1a.y, p1);
    p1 = fmaf(xa.z, z1a.z, p1); p1 = fmaf(xa.w, z1a.w, p1);
    p1 = fmaf(xb.x, z1b.x, p1); p1 = fmaf(xb.y, z1b.y, p1);
    p1 = fmaf(xb.z, z1b.z, p1); p1 = fmaf(xb.w, z1b.w, p1);

    p2 = fmaf(xa.x, z2a.x, p2); p2 = fmaf(xa.y, z2a.y, p2);
    p2 = fmaf(xa.z, z2a.z, p2); p2 = fmaf(xa.w, z2a.w, p2);
    p2 = fmaf(xb.x, z2b.x, p2); p2 = fmaf(xb.y, z2b.y, p2);
    p2 = fmaf(xb.z, z2b.z, p2); p2 = fmaf(xb.w, z2b.w, p2);

    p3 = fmaf(xa.x, z3a.x, p3); p3 = fmaf(xa.y, z3a.y, p3);
    p3 = fmaf(xa.z, z3a.z, p3); p3 = fmaf(xa.w, z3a.w, p3);
    p3 = fmaf(xb.x, z3b.x, p3); p3 = fmaf(xb.y, z3b.y, p3);
    p3 = fmaf(xb.z, z3b.z, p3); p3 = fmaf(xb.w, z3b.w, p3);

    float send01 = (l & 1) ? p0 : p1;
    float recv01 = __shfl_xor(send01, 1);
    float a01 = ((l & 1) ? p1 : p0) + recv01;
    float send23 = (l & 1) ? p2 : p3;
    float recv23 = __shfl_xor(send23, 1);
    float a23 = ((l & 1) ? p3 : p2) + recv23;
    float send = (l & 2) ? a01 : a23;
    float recv = __shfl_xor(send, 2);
    float r = ((l & 2) ? a23 : a01) + recv;

    out[t] = tanhf(r);
}

// ---------------------------------------------------------------------------
// Tier-3 fallback: direct quadratic form per edge (no workspace).
// ---------------------------------------------------------------------------
__global__ void edge_direct_kernel(const float* __restrict__ x,
                                   const float* __restrict__ T,
                                   const int* __restrict__ src,
                                   const int* __restrict__ dst,
                                   float* __restrict__ out,
                                   int n_edges) {
    int e = blockIdx.x * blockDim.x + threadIdx.x;
    if (e >= n_edges) return;

    const int s = src[e];
    const int d = dst[e];

    float xs[IN_CH], xd[IN_CH];
#pragma unroll
    for (int j = 0; j < IN_CH; ++j) {
        xs[j] = x[(size_t)s * IN_CH + j];
        xd[j] = x[(size_t)d * IN_CH + j];
    }

    float resv[K_OUT];
#pragma unroll
    for (int k = 0; k < K_OUT; ++k) {
        float acc = 0.f;
        for (int i = 0; i < IN_CH; ++i) {
            const float* Trow = T + ((size_t)k * IN_CH + i) * IN_CH;
            float yi = 0.f;
#pragma unroll
            for (int j = 0; j < IN_CH; ++j)
                yi = fmaf(Trow[j], xd[j], yi);
            acc = fmaf(xs[i], yi, acc);
        }
        resv[k] = tanhf(acc);
    }
    ((float4*)out)[e] = make_float4(resv[0], resv[1], resv[2], resv[3]);
}

extern "C" void kernel_launch(void* const* d_in, const int* in_sizes, int n_in,
                              void* d_out, int out_size, void* d_ws, size_t ws_size,
                              hipStream_t stream) {
    const float* x  = (const float*)d_in[0];
    const int*   ei = (const int*)d_in[1];
    const float* T  = (const float*)d_in[2];
    float* out      = (float*)d_out;

    const int n_nodes = in_sizes[0] / IN_CH;
    const int n_edges = in_sizes[1] / 2;
    const int* src = ei;
    const int* dst = ei + n_edges;

    // Workspace layout (256B-aligned)
    const size_t z_bytes  = (size_t)n_nodes * K_OUT * IN_CH * sizeof(float);
    const size_t meta_off = (z_bytes + 255) & ~(size_t)255;
    const size_t rec_off  = meta_off + 1024;
    const size_t p_off    = rec_off + (((size_t)n_edges * sizeof(unsigned int) + 255) & ~(size_t)255);
    const size_t res_off  = p_off + (((size_t)n_edges * sizeof(int) + 255) & ~(size_t)255);
    const size_t need_full = res_off + (size_t)n_edges * K_OUT * sizeof(__half);

    const int threads = 256;
    const int eblocks = (n_edges + threads - 1) / threads;

    if (ws_size >= need_full && n_nodes < 65536) {
        float*        z    = (float*)d_ws;
        int*          meta = (int*)((char*)d_ws + meta_off);
        unsigned int* rec  = (unsigned int*)((char*)d_ws + rec_off);
        int*          p    = (int*)((char*)d_ws + p_off);
        __half*       res  = (__half*)((char*)d_ws + res_off);

        precompute_z_kernel<<<2048, 128, 0, stream>>>(x, T, z, n_nodes);
        zero_meta_kernel<<<1, 256, 0, stream>>>(meta);
        hist_kernel<<<1024, 256, 0, stream>>>(src, dst, meta, n_edges, n_nodes);
        scan_kernel<<<1, 64, 0, stream>>>(meta);
        scatter_kernel<<<(n_edges + SORT_TILE - 1) / SORT_TILE, SORT_THREADS, 0, stream>>>(
            src, dst, meta, rec, p, n_edges, n_nodes);
        edge_kernel_sorted<<<2048, 256, 0, stream>>>(x, z, rec, meta + M_BO, res);
        permute_kernel<<<eblocks, threads, 0, stream>>>(res, p, (float4*)out, n_edges);
    } else if (ws_size >= z_bytes) {
        float* z = (float*)d_ws;
        precompute_z_kernel<<<2048, 128, 0, stream>>>(x, T, z, n_nodes);
        const long long total = (long long)n_edges * 4;
        const int blocks = (int)((total + threads - 1) / threads);
        edge_kernel_quad<<<blocks, threads, 0, stream>>>(x, z, src, dst, out, n_edges);
    } else {
        edge_direct_kernel<<<eblocks, threads, 0, stream>>>(x, T, src, dst, out, n_edges);
    }
}

// Round 6
// 100.386 us; speedup vs baseline: 1.5552x; 1.5552x over previous
//
#include <hip/hip_runtime.h>
#include <hip/hip_fp16.h>
#include <math.h>

#define IN_CH 32
#define K_OUT 4

typedef _Float16 h2_t __attribute__((ext_vector_type(2)));

// fp16x2 dot with fp32 accumulate: uses v_dot2_f32_f16 when available.
__device__ __forceinline__ float dot2acc(unsigned int a, unsigned int b, float c) {
#if defined(__has_builtin)
#if __has_builtin(__builtin_amdgcn_fdot2)
    return __builtin_amdgcn_fdot2(__builtin_bit_cast(h2_t, a),
                                  __builtin_bit_cast(h2_t, b), c, false);
#else
    __half2 ha = *(__half2*)&a, hb = *(__half2*)&b;
    float2 fa = __half22float2(ha), fb = __half22float2(hb);
    return fmaf(fa.y, fb.y, fmaf(fa.x, fb.x, c));
#endif
#else
    __half2 ha = *(__half2*)&a, hb = *(__half2*)&b;
    float2 fa = __half22float2(ha), fb = __half22float2(hb);
    return fmaf(fa.y, fb.y, fmaf(fa.x, fb.x, c));
#endif
}

// ---------------------------------------------------------------------------
// z16[n][k][i] = fp16( sum_j T[k][i][j] * x[n][j] ), fp32 accumulation.
// 128 threads = one (k,i) each; T staged in LDS.
// ---------------------------------------------------------------------------
__global__ void precompute_z16_kernel(const float* __restrict__ x,
                                      const float* __restrict__ T,
                                      __half* __restrict__ z16,
                                      int n_nodes) {
    __shared__ float Ts[K_OUT * IN_CH * IN_CH];
    for (int t = threadIdx.x; t < K_OUT * IN_CH * IN_CH; t += blockDim.x)
        Ts[t] = T[t];
    __syncthreads();

    const int ki = threadIdx.x;          // 0..127 -> k = ki>>5, i = ki&31
    const float* Trow = Ts + ki * IN_CH;

    for (int n = blockIdx.x; n < n_nodes; n += gridDim.x) {
        const float* xr = x + (size_t)n * IN_CH;
        float sum = 0.f;
#pragma unroll
        for (int j = 0; j < IN_CH; ++j)
            sum = fmaf(Trow[j], xr[j], sum);
        z16[(size_t)n * (K_OUT * IN_CH) + ki] = __float2half(sum);
    }
}

// x16[n][j] = fp16(x[n][j]); each thread converts 8 elements.
__global__ void x16_convert_kernel(const float* __restrict__ x,
                                   __half* __restrict__ x16,
                                   int total8) {
    int t = blockIdx.x * blockDim.x + threadIdx.x;
    if (t >= total8) return;
    const float4* xin = (const float4*)x + (size_t)t * 2;
    float4 a = xin[0];
    float4 b = xin[1];
    __half2 h0 = __floats2half2_rn(a.x, a.y);
    __half2 h1 = __floats2half2_rn(a.z, a.w);
    __half2 h2 = __floats2half2_rn(b.x, b.y);
    __half2 h3 = __floats2half2_rn(b.z, b.w);
    uint4 pack;
    pack.x = *(unsigned int*)&h0;
    pack.y = *(unsigned int*)&h1;
    pack.z = *(unsigned int*)&h2;
    pack.w = *(unsigned int*)&h3;
    ((uint4*)x16)[t] = pack;
}

// ---------------------------------------------------------------------------
// Main edge kernel: quad per edge, fp16 operands, fp32 accumulate.
// Per edge (whole quad): src/dst broadcast + 64B x16 row (1 line) +
// 256B z16 row (4 lines) + coalesced 16B fp32 output store.
// Lane l owns channels [8l, 8l+8); quad shfl-reduce leaves lane l = maps[e][l].
// ---------------------------------------------------------------------------
__global__ __launch_bounds__(256)
void edge_kernel_quad16(const __half* __restrict__ x16,
                        const __half* __restrict__ z16,
                        const int* __restrict__ src,
                        const int* __restrict__ dst,
                        float* __restrict__ out,
                        int n_edges) {
    const int t = blockIdx.x * blockDim.x + threadIdx.x;
    const int e = t >> 2;
    const int l = t & 3;
    if (e >= n_edges) return;

    const int s = src[e];
    const int d = dst[e];

    // x row = 32 halves = 4 uint4; lane takes uint4 #l (8 halves)
    const uint4 xv = ((const uint4*)x16)[(size_t)s * 4 + l];
    // z row = 128 halves = 16 uint4; slab k occupies uint4 [4k, 4k+4); lane takes +l
    const uint4* zrow = (const uint4*)z16 + (size_t)d * 16;
    const uint4 z0 = zrow[0 + l];
    const uint4 z1 = zrow[4 + l];
    const uint4 z2 = zrow[8 + l];
    const uint4 z3 = zrow[12 + l];

    float p0 = 0.f, p1 = 0.f, p2 = 0.f, p3 = 0.f;
    p0 = dot2acc(xv.x, z0.x, p0); p0 = dot2acc(xv.y, z0.y, p0);
    p0 = dot2acc(xv.z, z0.z, p0); p0 = dot2acc(xv.w, z0.w, p0);

    p1 = dot2acc(xv.x, z1.x, p1); p1 = dot2acc(xv.y, z1.y, p1);
    p1 = dot2acc(xv.z, z1.z, p1); p1 = dot2acc(xv.w, z1.w, p1);

    p2 = dot2acc(xv.x, z2.x, p2); p2 = dot2acc(xv.y, z2.y, p2);
    p2 = dot2acc(xv.z, z2.z, p2); p2 = dot2acc(xv.w, z2.w, p2);

    p3 = dot2acc(xv.x, z3.x, p3); p3 = dot2acc(xv.y, z3.y, p3);
    p3 = dot2acc(xv.z, z3.z, p3); p3 = dot2acc(xv.w, z3.w, p3);

    // Quad transpose-reduce: lane l ends with full maps[e][l].
    float send01 = (l & 1) ? p0 : p1;
    float recv01 = __shfl_xor(send01, 1);
    float a01 = ((l & 1) ? p1 : p0) + recv01;
    float send23 = (l & 1) ? p2 : p3;
    float recv23 = __shfl_xor(send23, 1);
    float a23 = ((l & 1) ? p3 : p2) + recv23;
    float send = (l & 2) ? a01 : a23;
    float recv = __shfl_xor(send, 2);
    float r = ((l & 2) ? a23 : a01) + recv;

    out[t] = tanhf(r);   // coalesced 4B/lane
}

// ---------------------------------------------------------------------------
// Fallback: direct quadratic form per edge (no workspace).
// ---------------------------------------------------------------------------
__global__ void edge_direct_kernel(const float* __restrict__ x,
                                   const float* __restrict__ T,
                                   const int* __restrict__ src,
                                   const int* __restrict__ dst,
                                   float* __restrict__ out,
                                   int n_edges) {
    int e = blockIdx.x * blockDim.x + threadIdx.x;
    if (e >= n_edges) return;

    const int s = src[e];
    const int d = dst[e];

    float xs[IN_CH], xd[IN_CH];
#pragma unroll
    for (int j = 0; j < IN_CH; ++j) {
        xs[j] = x[(size_t)s * IN_CH + j];
        xd[j] = x[(size_t)d * IN_CH + j];
    }

    float resv[K_OUT];
#pragma unroll
    for (int k = 0; k < K_OUT; ++k) {
        float acc = 0.f;
        for (int i = 0; i < IN_CH; ++i) {
            const float* Trow = T + ((size_t)k * IN_CH + i) * IN_CH;
            float yi = 0.f;
#pragma unroll
            for (int j = 0; j < IN_CH; ++j)
                yi = fmaf(Trow[j], xd[j], yi);
            acc = fmaf(xs[i], yi, acc);
        }
        resv[k] = tanhf(acc);
    }
    ((float4*)out)[e] = make_float4(resv[0], resv[1], resv[2], resv[3]);
}

extern "C" void kernel_launch(void* const* d_in, const int* in_sizes, int n_in,
                              void* d_out, int out_size, void* d_ws, size_t ws_size,
                              hipStream_t stream) {
    const float* x  = (const float*)d_in[0];
    const int*   ei = (const int*)d_in[1];
    const float* T  = (const float*)d_in[2];
    float* out      = (float*)d_out;

    const int n_nodes = in_sizes[0] / IN_CH;
    const int n_edges = in_sizes[1] / 2;
    const int* src = ei;
    const int* dst = ei + n_edges;

    // Workspace: z16 then x16 (both 256B-aligned)
    const size_t z16_bytes = (size_t)n_nodes * K_OUT * IN_CH * sizeof(__half);
    const size_t x16_off   = (z16_bytes + 255) & ~(size_t)255;
    const size_t need      = x16_off + (size_t)n_nodes * IN_CH * sizeof(__half);

    const int threads = 256;

    if (ws_size >= need) {
        __half* z16 = (__half*)d_ws;
        __half* x16 = (__half*)((char*)d_ws + x16_off);

        precompute_z16_kernel<<<2048, 128, 0, stream>>>(x, T, z16, n_nodes);

        const int total8 = (n_nodes * IN_CH) / 8;
        x16_convert_kernel<<<(total8 + threads - 1) / threads, threads, 0, stream>>>(
            x, x16, total8);

        const long long total = (long long)n_edges * 4;
        const int blocks = (int)((total + threads - 1) / threads);
        edge_kernel_quad16<<<blocks, threads, 0, stream>>>(
            x16, z16, src, dst, out, n_edges);
    } else {
        const int eblocks = (n_edges + threads - 1) / threads;
        edge_direct_kernel<<<eblocks, threads, 0, stream>>>(x, T, src, dst, out, n_edges);
    }
}

// Round 7
// 98.037 us; speedup vs baseline: 1.5924x; 1.0240x over previous
//
#include <hip/hip_runtime.h>
#include <hip/hip_fp16.h>
#include <math.h>

#define IN_CH 32
#define K_OUT 4

typedef _Float16 h2_t __attribute__((ext_vector_type(2)));

// fp16x2 dot with fp32 accumulate: uses v_dot2_f32_f16 when available.
__device__ __forceinline__ float dot2acc(unsigned int a, unsigned int b, float c) {
#if defined(__has_builtin)
#if __has_builtin(__builtin_amdgcn_fdot2)
    return __builtin_amdgcn_fdot2(__builtin_bit_cast(h2_t, a),
                                  __builtin_bit_cast(h2_t, b), c, false);
#else
    __half2 ha = *(__half2*)&a, hb = *(__half2*)&b;
    float2 fa = __half22float2(ha), fb = __half22float2(hb);
    return fmaf(fa.y, fb.y, fmaf(fa.x, fb.x, c));
#endif
#else
    __half2 ha = *(__half2*)&a, hb = *(__half2*)&b;
    float2 fa = __half22float2(ha), fb = __half22float2(hb);
    return fmaf(fa.y, fb.y, fmaf(fa.x, fb.x, c));
#endif
}

// ---------------------------------------------------------------------------
// Fused prep: z16[n][k][i] = fp16( sum_j T[k][i][j] * x[n][j] )  (fp32 accum)
//             x16[n][j]    = fp16( x[n][j] )
// 128 threads = one (k,i) each; T staged in LDS; x row reused from L1 for the
// fp16 conversion (threads 0..31).
// ---------------------------------------------------------------------------
__global__ void prep_kernel(const float* __restrict__ x,
                            const float* __restrict__ T,
                            __half* __restrict__ z16,
                            __half* __restrict__ x16,
                            int n_nodes) {
    __shared__ float Ts[K_OUT * IN_CH * IN_CH];
    for (int t = threadIdx.x; t < K_OUT * IN_CH * IN_CH; t += blockDim.x)
        Ts[t] = T[t];
    __syncthreads();

    const int ki = threadIdx.x;          // 0..127 -> k = ki>>5, i = ki&31
    const float* Trow = Ts + ki * IN_CH;

    for (int n = blockIdx.x; n < n_nodes; n += gridDim.x) {
        const float* xr = x + (size_t)n * IN_CH;
        float sum = 0.f;
#pragma unroll
        for (int j = 0; j < IN_CH; ++j)
            sum = fmaf(Trow[j], xr[j], sum);
        z16[(size_t)n * (K_OUT * IN_CH) + ki] = __float2half(sum);
        if (ki < IN_CH)
            x16[(size_t)n * IN_CH + ki] = __float2half(xr[ki]);
    }
}

// ---------------------------------------------------------------------------
// Main edge kernel: quad per edge, fp16 operands, fp32 accumulate.
// Per edge (whole quad): src/dst broadcast + 64B x16 row (1 line) +
// 256B z16 row (4 lines) + coalesced 16B fp32 output store.
// Lane l owns channels [8l, 8l+8); quad shfl-reduce leaves lane l = maps[e][l].
// Fetch-bound roofline: 5 lines/edge random-gather at ~3.5 TB/s fabric.
// ---------------------------------------------------------------------------
__global__ __launch_bounds__(256)
void edge_kernel_quad16(const __half* __restrict__ x16,
                        const __half* __restrict__ z16,
                        const int* __restrict__ src,
                        const int* __restrict__ dst,
                        float* __restrict__ out,
                        int n_edges) {
    const int t = blockIdx.x * blockDim.x + threadIdx.x;
    const int e = t >> 2;
    const int l = t & 3;
    if (e >= n_edges) return;

    const int s = src[e];
    const int d = dst[e];

    // x row = 32 halves = 4 uint4; lane takes uint4 #l (8 halves)
    const uint4 xv = ((const uint4*)x16)[(size_t)s * 4 + l];
    // z row = 128 halves = 16 uint4; slab k occupies uint4 [4k, 4k+4); lane takes +l
    const uint4* zrow = (const uint4*)z16 + (size_t)d * 16;
    const uint4 z0 = zrow[0 + l];
    const uint4 z1 = zrow[4 + l];
    const uint4 z2 = zrow[8 + l];
    const uint4 z3 = zrow[12 + l];

    float p0 = 0.f, p1 = 0.f, p2 = 0.f, p3 = 0.f;
    p0 = dot2acc(xv.x, z0.x, p0); p0 = dot2acc(xv.y, z0.y, p0);
    p0 = dot2acc(xv.z, z0.z, p0); p0 = dot2acc(xv.w, z0.w, p0);

    p1 = dot2acc(xv.x, z1.x, p1); p1 = dot2acc(xv.y, z1.y, p1);
    p1 = dot2acc(xv.z, z1.z, p1); p1 = dot2acc(xv.w, z1.w, p1);

    p2 = dot2acc(xv.x, z2.x, p2); p2 = dot2acc(xv.y, z2.y, p2);
    p2 = dot2acc(xv.z, z2.z, p2); p2 = dot2acc(xv.w, z2.w, p2);

    p3 = dot2acc(xv.x, z3.x, p3); p3 = dot2acc(xv.y, z3.y, p3);
    p3 = dot2acc(xv.z, z3.z, p3); p3 = dot2acc(xv.w, z3.w, p3);

    // Quad transpose-reduce: lane l ends with full maps[e][l].
    float send01 = (l & 1) ? p0 : p1;
    float recv01 = __shfl_xor(send01, 1);
    float a01 = ((l & 1) ? p1 : p0) + recv01;
    float send23 = (l & 1) ? p2 : p3;
    float recv23 = __shfl_xor(send23, 1);
    float a23 = ((l & 1) ? p3 : p2) + recv23;
    float send = (l & 2) ? a01 : a23;
    float recv = __shfl_xor(send, 2);
    float r = ((l & 2) ? a23 : a01) + recv;

    out[t] = tanhf(r);   // coalesced 4B/lane
}

// ---------------------------------------------------------------------------
// Fallback: direct quadratic form per edge (no workspace).
// ---------------------------------------------------------------------------
__global__ void edge_direct_kernel(const float* __restrict__ x,
                                   const float* __restrict__ T,
                                   const int* __restrict__ src,
                                   const int* __restrict__ dst,
                                   float* __restrict__ out,
                                   int n_edges) {
    int e = blockIdx.x * blockDim.x + threadIdx.x;
    if (e >= n_edges) return;

    const int s = src[e];
    const int d = dst[e];

    float xs[IN_CH], xd[IN_CH];
#pragma unroll
    for (int j = 0; j < IN_CH; ++j) {
        xs[j] = x[(size_t)s * IN_CH + j];
        xd[j] = x[(size_t)d * IN_CH + j];
    }

    float resv[K_OUT];
#pragma unroll
    for (int k = 0; k < K_OUT; ++k) {
        float acc = 0.f;
        for (int i = 0; i < IN_CH; ++i) {
            const float* Trow = T + ((size_t)k * IN_CH + i) * IN_CH;
            float yi = 0.f;
#pragma unroll
            for (int j = 0; j < IN_CH; ++j)
                yi = fmaf(Trow[j], xd[j], yi);
            acc = fmaf(xs[i], yi, acc);
        }
        resv[k] = tanhf(acc);
    }
    ((float4*)out)[e] = make_float4(resv[0], resv[1], resv[2], resv[3]);
}

extern "C" void kernel_launch(void* const* d_in, const int* in_sizes, int n_in,
                              void* d_out, int out_size, void* d_ws, size_t ws_size,
                              hipStream_t stream) {
    const float* x  = (const float*)d_in[0];
    const int*   ei = (const int*)d_in[1];
    const float* T  = (const float*)d_in[2];
    float* out      = (float*)d_out;

    const int n_nodes = in_sizes[0] / IN_CH;
    const int n_edges = in_sizes[1] / 2;
    const int* src = ei;
    const int* dst = ei + n_edges;

    // Workspace: z16 then x16 (both 256B-aligned)
    const size_t z16_bytes = (size_t)n_nodes * K_OUT * IN_CH * sizeof(__half);
    const size_t x16_off   = (z16_bytes + 255) & ~(size_t)255;
    const size_t need      = x16_off + (size_t)n_nodes * IN_CH * sizeof(__half);

    const int threads = 256;

    if (ws_size >= need) {
        __half* z16 = (__half*)d_ws;
        __half* x16 = (__half*)((char*)d_ws + x16_off);

        prep_kernel<<<2048, 128, 0, stream>>>(x, T, z16, x16, n_nodes);

        const long long total = (long long)n_edges * 4;
        const int blocks = (int)((total + threads - 1) / threads);
        edge_kernel_quad16<<<blocks, threads, 0, stream>>>(
            x16, z16, src, dst, out, n_edges);
    } else {
        const int eblocks = (n_edges + threads - 1) / threads;
        edge_direct_kernel<<<eblocks, threads, 0, stream>>>(x, T, src, dst, out, n_edges);
    }
}

// Round 8
// 91.552 us; speedup vs baseline: 1.7053x; 1.0708x over previous
//
#include <hip/hip_runtime.h>
#include <hip/hip_fp16.h>
#include <math.h>

#define IN_CH 32
#define K_OUT 4

typedef _Float16 h2_t __attribute__((ext_vector_type(2)));

// fp16x2 dot with fp32 accumulate: uses v_dot2_f32_f16 when available.
__device__ __forceinline__ float dot2acc(unsigned int a, unsigned int b, float c) {
#if defined(__has_builtin)
#if __has_builtin(__builtin_amdgcn_fdot2)
    return __builtin_amdgcn_fdot2(__builtin_bit_cast(h2_t, a),
                                  __builtin_bit_cast(h2_t, b), c, false);
#else
    __half2 ha = *(__half2*)&a, hb = *(__half2*)&b;
    float2 fa = __half22float2(ha), fb = __half22float2(hb);
    return fmaf(fa.y, fb.y, fmaf(fa.x, fb.x, c));
#endif
#else
    __half2 ha = *(__half2*)&a, hb = *(__half2*)&b;
    float2 fa = __half22float2(ha), fb = __half22float2(hb);
    return fmaf(fa.y, fb.y, fmaf(fa.x, fb.x, c));
#endif
}

// ---------------------------------------------------------------------------
// Fused prep: z16[n][k][i] = fp16( sum_j T[k][i][j] * x[n][j] )  (fp32 accum)
//             x16[n][j]    = fp16( x[n][j] )
// NO LDS: lane ki keeps T-row [ki][0..31] in 32 VGPRs (loaded once; the old
// LDS version had a 32-way bank conflict: row stride 128B -> all 64 lanes of
// a wave on one bank for every read). x row: 8 uniform float4 loads = one
// 128B line, L1-broadcast. 4 independent accumulators for ILP.
// ---------------------------------------------------------------------------
__global__ __launch_bounds__(128)
void prep_kernel(const float* __restrict__ x,
                 const float* __restrict__ T,
                 __half* __restrict__ z16,
                 __half* __restrict__ x16,
                 int n_nodes) {
    const int ki = threadIdx.x;          // 0..127 -> k = ki>>5, i = ki&31

    // Per-lane T row in registers (lane-varying address, coalesced loads).
    float4 t0 = ((const float4*)(T + (size_t)ki * IN_CH))[0];
    float4 t1 = ((const float4*)(T + (size_t)ki * IN_CH))[1];
    float4 t2 = ((const float4*)(T + (size_t)ki * IN_CH))[2];
    float4 t3 = ((const float4*)(T + (size_t)ki * IN_CH))[3];
    float4 t4 = ((const float4*)(T + (size_t)ki * IN_CH))[4];
    float4 t5 = ((const float4*)(T + (size_t)ki * IN_CH))[5];
    float4 t6 = ((const float4*)(T + (size_t)ki * IN_CH))[6];
    float4 t7 = ((const float4*)(T + (size_t)ki * IN_CH))[7];

    for (int n = blockIdx.x; n < n_nodes; n += gridDim.x) {
        const float4* xr = (const float4*)(x + (size_t)n * IN_CH);
        float4 x0 = xr[0], x1 = xr[1], x2 = xr[2], x3 = xr[3];
        float4 x4 = xr[4], x5 = xr[5], x6 = xr[6], x7 = xr[7];

        // 4 independent accumulators (break the 32-deep FMA chain)
        float a0 = 0.f, a1 = 0.f, a2 = 0.f, a3 = 0.f;
        a0 = fmaf(t0.x, x0.x, a0); a1 = fmaf(t0.y, x0.y, a1);
        a2 = fmaf(t0.z, x0.z, a2); a3 = fmaf(t0.w, x0.w, a3);
        a0 = fmaf(t1.x, x1.x, a0); a1 = fmaf(t1.y, x1.y, a1);
        a2 = fmaf(t1.z, x1.z, a2); a3 = fmaf(t1.w, x1.w, a3);
        a0 = fmaf(t2.x, x2.x, a0); a1 = fmaf(t2.y, x2.y, a1);
        a2 = fmaf(t2.z, x2.z, a2); a3 = fmaf(t2.w, x2.w, a3);
        a0 = fmaf(t3.x, x3.x, a0); a1 = fmaf(t3.y, x3.y, a1);
        a2 = fmaf(t3.z, x3.z, a2); a3 = fmaf(t3.w, x3.w, a3);
        a0 = fmaf(t4.x, x4.x, a0); a1 = fmaf(t4.y, x4.y, a1);
        a2 = fmaf(t4.z, x4.z, a2); a3 = fmaf(t4.w, x4.w, a3);
        a0 = fmaf(t5.x, x5.x, a0); a1 = fmaf(t5.y, x5.y, a1);
        a2 = fmaf(t5.z, x5.z, a2); a3 = fmaf(t5.w, x5.w, a3);
        a0 = fmaf(t6.x, x6.x, a0); a1 = fmaf(t6.y, x6.y, a1);
        a2 = fmaf(t6.z, x6.z, a2); a3 = fmaf(t6.w, x6.w, a3);
        a0 = fmaf(t7.x, x7.x, a0); a1 = fmaf(t7.y, x7.y, a1);
        a2 = fmaf(t7.z, x7.z, a2); a3 = fmaf(t7.w, x7.w, a3);

        z16[(size_t)n * (K_OUT * IN_CH) + ki] = __float2half((a0 + a1) + (a2 + a3));

        if (ki < IN_CH)
            x16[(size_t)n * IN_CH + ki] = __float2half(x[(size_t)n * IN_CH + ki]);
    }
}

// ---------------------------------------------------------------------------
// Main edge kernel: quad per edge, fp16 operands, fp32 accumulate.
// Per edge (whole quad): src/dst broadcast + 64B x16 row (1 line) +
// 256B z16 row (4 lines) + coalesced 16B fp32 output store.
// Lane l owns channels [8l, 8l+8); quad shfl-reduce leaves lane l = maps[e][l].
// Fetch-bound roofline: 5 lines/edge random-gather at ~3.5-3.8 TB/s fabric
// (measured ceiling for random line fetches across rounds 1/2/6/7).
// ---------------------------------------------------------------------------
__global__ __launch_bounds__(256)
void edge_kernel_quad16(const __half* __restrict__ x16,
                        const __half* __restrict__ z16,
                        const int* __restrict__ src,
                        const int* __restrict__ dst,
                        float* __restrict__ out,
                        int n_edges) {
    const int t = blockIdx.x * blockDim.x + threadIdx.x;
    const int e = t >> 2;
    const int l = t & 3;
    if (e >= n_edges) return;

    const int s = src[e];
    const int d = dst[e];

    // x row = 32 halves = 4 uint4; lane takes uint4 #l (8 halves)
    const uint4 xv = ((const uint4*)x16)[(size_t)s * 4 + l];
    // z row = 128 halves = 16 uint4; slab k occupies uint4 [4k, 4k+4); lane takes +l
    const uint4* zrow = (const uint4*)z16 + (size_t)d * 16;
    const uint4 z0 = zrow[0 + l];
    const uint4 z1 = zrow[4 + l];
    const uint4 z2 = zrow[8 + l];
    const uint4 z3 = zrow[12 + l];

    float p0 = 0.f, p1 = 0.f, p2 = 0.f, p3 = 0.f;
    p0 = dot2acc(xv.x, z0.x, p0); p0 = dot2acc(xv.y, z0.y, p0);
    p0 = dot2acc(xv.z, z0.z, p0); p0 = dot2acc(xv.w, z0.w, p0);

    p1 = dot2acc(xv.x, z1.x, p1); p1 = dot2acc(xv.y, z1.y, p1);
    p1 = dot2acc(xv.z, z1.z, p1); p1 = dot2acc(xv.w, z1.w, p1);

    p2 = dot2acc(xv.x, z2.x, p2); p2 = dot2acc(xv.y, z2.y, p2);
    p2 = dot2acc(xv.z, z2.z, p2); p2 = dot2acc(xv.w, z2.w, p2);

    p3 = dot2acc(xv.x, z3.x, p3); p3 = dot2acc(xv.y, z3.y, p3);
    p3 = dot2acc(xv.z, z3.z, p3); p3 = dot2acc(xv.w, z3.w, p3);

    // Quad transpose-reduce: lane l ends with full maps[e][l].
    float send01 = (l & 1) ? p0 : p1;
    float recv01 = __shfl_xor(send01, 1);
    float a01 = ((l & 1) ? p1 : p0) + recv01;
    float send23 = (l & 1) ? p2 : p3;
    float recv23 = __shfl_xor(send23, 1);
    float a23 = ((l & 1) ? p3 : p2) + recv23;
    float send = (l & 2) ? a01 : a23;
    float recv = __shfl_xor(send, 2);
    float r = ((l & 2) ? a23 : a01) + recv;

    out[t] = tanhf(r);   // coalesced 4B/lane
}

// ---------------------------------------------------------------------------
// Fallback: direct quadratic form per edge (no workspace).
// ---------------------------------------------------------------------------
__global__ void edge_direct_kernel(const float* __restrict__ x,
                                   const float* __restrict__ T,
                                   const int* __restrict__ src,
                                   const int* __restrict__ dst,
                                   float* __restrict__ out,
                                   int n_edges) {
    int e = blockIdx.x * blockDim.x + threadIdx.x;
    if (e >= n_edges) return;

    const int s = src[e];
    const int d = dst[e];

    float xs[IN_CH], xd[IN_CH];
#pragma unroll
    for (int j = 0; j < IN_CH; ++j) {
        xs[j] = x[(size_t)s * IN_CH + j];
        xd[j] = x[(size_t)d * IN_CH + j];
    }

    float resv[K_OUT];
#pragma unroll
    for (int k = 0; k < K_OUT; ++k) {
        float acc = 0.f;
        for (int i = 0; i < IN_CH; ++i) {
            const float* Trow = T + ((size_t)k * IN_CH + i) * IN_CH;
            float yi = 0.f;
#pragma unroll
            for (int j = 0; j < IN_CH; ++j)
                yi = fmaf(Trow[j], xd[j], yi);
            acc = fmaf(xs[i], yi, acc);
        }
        resv[k] = tanhf(acc);
    }
    ((float4*)out)[e] = make_float4(resv[0], resv[1], resv[2], resv[3]);
}

extern "C" void kernel_launch(void* const* d_in, const int* in_sizes, int n_in,
                              void* d_out, int out_size, void* d_ws, size_t ws_size,
                              hipStream_t stream) {
    const float* x  = (const float*)d_in[0];
    const int*   ei = (const int*)d_in[1];
    const float* T  = (const float*)d_in[2];
    float* out      = (float*)d_out;

    const int n_nodes = in_sizes[0] / IN_CH;
    const int n_edges = in_sizes[1] / 2;
    const int* src = ei;
    const int* dst = ei + n_edges;

    // Workspace: z16 then x16 (both 256B-aligned)
    const size_t z16_bytes = (size_t)n_nodes * K_OUT * IN_CH * sizeof(__half);
    const size_t x16_off   = (z16_bytes + 255) & ~(size_t)255;
    const size_t need      = x16_off + (size_t)n_nodes * IN_CH * sizeof(__half);

    const int threads = 256;

    if (ws_size >= need) {
        __half* z16 = (__half*)d_ws;
        __half* x16 = (__half*)((char*)d_ws + x16_off);

        prep_kernel<<<4096, 128, 0, stream>>>(x, T, z16, x16, n_nodes);

        const long long total = (long long)n_edges * 4;
        const int blocks = (int)((total + threads - 1) / threads);
        edge_kernel_quad16<<<blocks, threads, 0, stream>>>(
            x16, z16, src, dst, out, n_edges);
    } else {
        const int eblocks = (n_edges + threads - 1) / threads;
        edge_direct_kernel<<<eblocks, threads, 0, stream>>>(x, T, src, dst, out, n_edges);
    }
}